// Round 1
// 771.296 us; speedup vs baseline: 1.1935x; 1.1935x over previous
//
#include <hip/hip_runtime.h>
#include <math.h>

#define B 8
#define N 2048
#define D 1024

#define BM 128
#define BN 128
#define BK 32

typedef __bf16 bf16;
typedef __bf16 bf16x8 __attribute__((ext_vector_type(8)));
typedef __bf16 bf16x4 __attribute__((ext_vector_type(4)));
typedef float f32x4 __attribute__((ext_vector_type(4)));

__device__ __forceinline__ void load_lds16(const void* g, void* l) {
    __builtin_amdgcn_global_load_lds((const __attribute__((address_space(1))) void*)g,
                                     (__attribute__((address_space(3))) void*)l, 16, 0, 0);
}

#define MFMA16(a, b, c) __builtin_amdgcn_mfma_f32_16x16x32_bf16(a, b, c, 0, 0, 0)
#define BARRIER() asm volatile("s_barrier" ::: "memory")
#define WAITV8() asm volatile("s_waitcnt vmcnt(8)" ::: "memory")
#define WAITV0() asm volatile("s_waitcnt vmcnt(0)" ::: "memory")

// ---------------------------------------------------------------------------
// Split fp32 x into bf16 hi + lo residual (hi = RN(x), lo = RN(x - hi)).
// ---------------------------------------------------------------------------
__global__ __launch_bounds__(256) void split_fp32(const float* __restrict__ x,
                                                  bf16* __restrict__ h,
                                                  bf16* __restrict__ l, long n)
{
    long i = ((long)blockIdx.x * 256 + threadIdx.x) * 4;
    if (i >= n) return;
    float4 v = *(const float4*)(x + i);
    float vs[4] = {v.x, v.y, v.z, v.w};
    bf16x4 hh, ll;
#pragma unroll
    for (int t = 0; t < 4; ++t) {
        bf16 hv = (bf16)vs[t];
        hh[t] = hv;
        ll[t] = (bf16)(vs[t] - (float)hv);
    }
    *(bf16x4*)(h + i) = hh;
    *(bf16x4*)(l + i) = ll;
}

// ---------------------------------------------------------------------------
// Transpose + split: in W [1024][1024] fp32 row-major -> WT_h/WT_l [1024][1024]
// bf16 with WT[d][k] = W[k][d]. LDS-tiled 64x64, both sides coalesced.
// ---------------------------------------------------------------------------
__global__ __launch_bounds__(256) void tsplit_1024(const float* __restrict__ W,
                                                   bf16* __restrict__ WT_h,
                                                   bf16* __restrict__ WT_l)
{
    __shared__ float tile[64][65];
    const int d0 = blockIdx.x * 64, k0 = blockIdx.y * 64;
    const int tx = threadIdx.x & 63, ty = threadIdx.x >> 6;   // tx: fast dim
#pragma unroll
    for (int r = 0; r < 16; ++r) {
        int kl = ty + r * 4;
        tile[kl][tx] = W[(size_t)(k0 + kl) * 1024 + d0 + tx];
    }
    __syncthreads();
#pragma unroll
    for (int r = 0; r < 16; ++r) {
        int dl = ty + r * 4;
        float v = tile[tx][dl];
        bf16 hv = (bf16)v;
        size_t idx = (size_t)(d0 + dl) * 1024 + k0 + tx;
        WT_h[idx] = hv;
        WT_l[idx] = (bf16)(v - (float)hv);
    }
}

// ---------------------------------------------------------------------------
// Old 128x128 NT MFMA GEMM (m97 structure). Retained ONLY for the tiny
// 1024^3 Wqk product (16 blocks at 256^2 would idle 94% of the chip;
// 64 blocks at 128^2 is better for this one).
// ---------------------------------------------------------------------------
template<int TERMS, int EPI>
__global__ __launch_bounds__(256) void gemm_nt_mfma(
    const bf16* __restrict__ Ah_g, const bf16* __restrict__ Al_g,
    const bf16* __restrict__ Bh_g, const bf16* __restrict__ Bl_g,
    bf16* __restrict__ Chi, bf16* __restrict__ Clo,
    float* __restrict__ Cf, const float* __restrict__ Text,
    float* __restrict__ Feat,
    int Mdim, int Ncdim, int Kdim, long sA, long sB, long sC)
{
    __shared__ bf16 Ah[BM][BK];
    __shared__ bf16 Bh[BN][BK];
    __shared__ bf16 Al[BM][BK];
    __shared__ bf16 Bl[BN][BK];

    const int tid = threadIdx.x;
    const int lane = tid & 63;
    const int wv = tid >> 6;
    const int wr = (wv >> 1) * 64;
    const int wc = (wv & 1) * 64;
    const int mfrag = lane & 15;
    const int quad = lane >> 4;

    const long z = blockIdx.z;
    const int row0 = blockIdx.y * BM;
    const int col0 = blockIdx.x * BN;

    const bf16* Abh = Ah_g + z * sA;
    const bf16* Abl = (TERMS == 3) ? (Al_g + z * sA) : nullptr;
    const bf16* Bbh = Bh_g + z * sB;
    const bf16* Bbl = (TERMS == 3) ? (Bl_g + z * sB) : nullptr;

    f32x4 acc[4][4] = {};

    for (int k0 = 0; k0 < Kdim; k0 += BK) {
#pragma unroll
        for (int q = 0; q < 2; ++q) {
            int c = q * 256 + tid;
            int row = c >> 2, kp = (c & 3) * 8;
            load_lds16(Abh + (long)(row0 + row) * Kdim + k0 + kp, &Ah[row][kp]);
            load_lds16(Bbh + (long)(col0 + row) * Kdim + k0 + kp, &Bh[row][kp]);
            if constexpr (TERMS == 3) {
                load_lds16(Abl + (long)(row0 + row) * Kdim + k0 + kp, &Al[row][kp]);
                load_lds16(Bbl + (long)(col0 + row) * Kdim + k0 + kp, &Bl[row][kp]);
            }
        }
        __syncthreads();

        bf16x8 a_h[4], b_h[4], a_l[4], b_l[4];
#pragma unroll
        for (int i = 0; i < 4; ++i) {
            a_h[i] = *(const bf16x8*)&Ah[wr + i * 16 + mfrag][quad * 8];
            b_h[i] = *(const bf16x8*)&Bh[wc + i * 16 + mfrag][quad * 8];
            if constexpr (TERMS == 3) {
                a_l[i] = *(const bf16x8*)&Al[wr + i * 16 + mfrag][quad * 8];
                b_l[i] = *(const bf16x8*)&Bl[wc + i * 16 + mfrag][quad * 8];
            }
        }
#pragma unroll
        for (int i = 0; i < 4; ++i)
#pragma unroll
            for (int j = 0; j < 4; ++j) {
                acc[i][j] = MFMA16(a_h[i], b_h[j], acc[i][j]);
                if constexpr (TERMS == 3) {
                    acc[i][j] = MFMA16(a_h[i], b_l[j], acc[i][j]);
                    acc[i][j] = MFMA16(a_l[i], b_h[j], acc[i][j]);
                }
            }
        __syncthreads();
    }

    const long cbase = z * sC;
    const bool wlo = (Clo != nullptr);
#pragma unroll
    for (int i = 0; i < 4; ++i) {
#pragma unroll
        for (int r = 0; r < 4; ++r) {
            int row = row0 + wr + i * 16 + quad * 4 + r;
#pragma unroll
            for (int j = 0; j < 4; ++j) {
                int col = col0 + wc + j * 16 + mfrag;
                long idx = cbase + (long)row * Ncdim + col;
                float v = acc[i][j][r];
                if constexpr (EPI == 0) {
                    bf16 h = (bf16)v;
                    Chi[idx] = h;
                    if (wlo) Clo[idx] = (bf16)(v - (float)h);
                } else if constexpr (EPI == 1) {
                    Cf[idx] = v;
                } else {
                    Cf[idx] = v;
                    Feat[idx] = v + Text[idx];
                }
            }
        }
    }
}

// ===========================================================================
// 256x256-tile 8-wave phased GEMMs (T2 swizzle + T3/T4 counted vmcnt + T5
// setprio). 512 threads = 2(M) x 4(N) waves, each owning a 128x64 sub-tile
// of 16x16x32 MFMA fragments. LDS 128 KiB -> 1 block/CU, 2 waves/SIMD.
//
// Staging: global_load_lds with LINEAR LDS dest; the XOR swizzle is applied
// to the per-lane GLOBAL source address and mirrored on the ds_read side
// (both-sides-or-neither rule). ds_read conflicts drop to 2-way (free).
//
// Sync: raw s_barrier (no vmcnt(0) drain); one counted s_waitcnt vmcnt(8)
// per K-tile that covers the PREVIOUS tile's 8 loads while the 8 just
// issued for the next tile stay in flight. Never vmcnt(0) in steady state.
//
// Numerics: per-accumulator MFMA order (k order, hh->hl->lh) is identical
// to the old kernel -> bit-identical outputs.
// ===========================================================================

// stage a 256-row x 32-col bf16 panel; LDS linear, source pre-swizzled.
__device__ __forceinline__ void stage32(const bf16* __restrict__ g, int Kd, int k0,
                                        bf16* l, int tid)
{
#pragma unroll
    for (int c = 0; c < 2; ++c) {
        int idx = c * 512 + tid;
        int row = idx >> 2;                    // 0..255
        int slot = idx & 3;                    // 16B slot within 64B row
        int kk = ((slot ^ ((row >> 1) & 3)) << 3);
        load_lds16(g + (long)row * Kd + k0 + kk, l + (size_t)idx * 8);
    }
}

// stage a 256-row x 64-col bf16 panel; LDS linear, source pre-swizzled.
__device__ __forceinline__ void stage64(const bf16* __restrict__ g, int Kd, int k0,
                                        bf16* l, int tid)
{
#pragma unroll
    for (int c = 0; c < 4; ++c) {
        int idx = c * 512 + tid;
        int row = idx >> 3;                    // 0..255
        int slot = idx & 7;                    // 16B slot within 128B row
        int kk = ((slot ^ (row & 7)) << 3);
        load_lds16(g + (long)row * Kd + k0 + kk, l + (size_t)idx * 8);
    }
}

__device__ __forceinline__ bf16x8 rd32(const bf16* l, int row, int quad) {
    return *(const bf16x8*)(l + row * 32 + ((quad ^ ((row >> 1) & 3)) << 3));
}
__device__ __forceinline__ bf16x8 rd64(const bf16* l, int row, int ks, int quad) {
    return *(const bf16x8*)(l + row * 64 + (((ks * 4 + quad) ^ (row & 7)) << 3));
}

// ---------------------------------------------------------------------------
// 3-term split-bf16 GEMM, BK=32, 3 phases per K-tile (hh / h*l / l*h).
// EPI: 0 = write bf16 hi (+lo if Clo), 1 = write fp32 Cf.
// ---------------------------------------------------------------------------
template<int EPI>
__global__ __launch_bounds__(512) void gemm256_3t(
    const bf16* __restrict__ Ah_g, const bf16* __restrict__ Al_g,
    const bf16* __restrict__ Bh_g, const bf16* __restrict__ Bl_g,
    bf16* __restrict__ Chi, bf16* __restrict__ Clo, float* __restrict__ Cf,
    int Ncdim, int Kdim, long sA, long sB, long sC)
{
    __shared__ __align__(16) bf16 lds[2][4][256 * 32];   // 128 KiB

    const int tid = threadIdx.x;
    const int lane = tid & 63;
    const int wv = tid >> 6;
    const int wrow = (wv >> 2) << 7;      // 0 or 128
    const int wcol = (wv & 3) << 6;       // 0,64,128,192
    const int mfrag = lane & 15;
    const int quad = lane >> 4;

    const long z = blockIdx.z;
    const int row0 = blockIdx.y * 256;
    const int col0 = blockIdx.x * 256;

    const bf16* Abh = Ah_g + z * sA + (long)row0 * Kdim;
    const bf16* Abl = Al_g + z * sA + (long)row0 * Kdim;
    const bf16* Bbh = Bh_g + z * sB + (long)col0 * Kdim;
    const bf16* Bbl = Bl_g + z * sB + (long)col0 * Kdim;

    f32x4 acc[8][4] = {};
    const int NT = Kdim >> 5;

    // prologue: stage tile 0 into buf 0 (8 loads/thread, waited at P1(0))
    stage32(Abh, Kdim, 0, lds[0][0], tid);
    stage32(Abl, Kdim, 0, lds[0][1], tid);
    stage32(Bbh, Kdim, 0, lds[0][2], tid);
    stage32(Bbl, Kdim, 0, lds[0][3], tid);

    for (int t = 0; t < NT; ++t) {
        const int cur = t & 1;
        const bf16* LAh = lds[cur][0];
        const bf16* LAl = lds[cur][1];
        const bf16* LBh = lds[cur][2];
        const bf16* LBl = lds[cur][3];

        // ---- P1: issue prefetch of t+1, counted wait for t, compute hi*hi
        if (t + 1 < NT) {
            const int k0 = (t + 1) << 5;
            stage32(Abh, Kdim, k0, lds[cur ^ 1][0], tid);
            stage32(Abl, Kdim, k0, lds[cur ^ 1][1], tid);
            stage32(Bbh, Kdim, k0, lds[cur ^ 1][2], tid);
            stage32(Bbl, Kdim, k0, lds[cur ^ 1][3], tid);
            WAITV8();       // tile t's 8 loads done; t+1's 8 stay in flight
        } else {
            WAITV0();
        }
        BARRIER();
        bf16x8 ah[8], bh[4];
#pragma unroll
        for (int i = 0; i < 8; ++i) ah[i] = rd32(LAh, wrow + i * 16 + mfrag, quad);
#pragma unroll
        for (int j = 0; j < 4; ++j) bh[j] = rd32(LBh, wcol + j * 16 + mfrag, quad);
        __builtin_amdgcn_s_setprio(1);
#pragma unroll
        for (int i = 0; i < 8; ++i)
#pragma unroll
            for (int j = 0; j < 4; ++j)
                acc[i][j] = MFMA16(ah[i], bh[j], acc[i][j]);
        __builtin_amdgcn_s_setprio(0);
        BARRIER();

        // ---- P2: hi*lo (ds_reads overlap other waves' P1 MFMA)
        bf16x8 bl[4];
#pragma unroll
        for (int j = 0; j < 4; ++j) bl[j] = rd32(LBl, wcol + j * 16 + mfrag, quad);
        BARRIER();
        __builtin_amdgcn_s_setprio(1);
#pragma unroll
        for (int i = 0; i < 8; ++i)
#pragma unroll
            for (int j = 0; j < 4; ++j)
                acc[i][j] = MFMA16(ah[i], bl[j], acc[i][j]);
        __builtin_amdgcn_s_setprio(0);
        BARRIER();

        // ---- P3: lo*hi
        bf16x8 al[8];
#pragma unroll
        for (int i = 0; i < 8; ++i) al[i] = rd32(LAl, wrow + i * 16 + mfrag, quad);
        BARRIER();
        __builtin_amdgcn_s_setprio(1);
#pragma unroll
        for (int i = 0; i < 8; ++i)
#pragma unroll
            for (int j = 0; j < 4; ++j)
                acc[i][j] = MFMA16(al[i], bh[j], acc[i][j]);
        __builtin_amdgcn_s_setprio(0);
        BARRIER();
    }

    // ---- epilogue ---- C/D layout: col = lane&15, row = quad*4 + reg
    const long cbase = z * sC;
    const bool wlo = (Clo != nullptr);
#pragma unroll
    for (int i = 0; i < 8; ++i) {
#pragma unroll
        for (int r = 0; r < 4; ++r) {
            int row = row0 + wrow + i * 16 + quad * 4 + r;
            long rbase = cbase + (long)row * Ncdim;
#pragma unroll
            for (int j = 0; j < 4; ++j) {
                int col = col0 + wcol + j * 16 + mfrag;
                float v = acc[i][j][r];
                if constexpr (EPI == 0) {
                    bf16 h = (bf16)v;
                    Chi[rbase + col] = h;
                    if (wlo) Clo[rbase + col] = (bf16)(v - (float)h);
                } else {
                    Cf[rbase + col] = v;
                }
            }
        }
    }
}

// ---------------------------------------------------------------------------
// 1-term GEMM, BK=64, 4 quadrant phases per K-tile.
// EPI: 0 = write bf16 hi ; 2 = PV epilogue (Cf = C fp32, Feat = C + Text).
// ---------------------------------------------------------------------------
template<int EPI>
__global__ __launch_bounds__(512) void gemm256_1t(
    const bf16* __restrict__ A_g, const bf16* __restrict__ B_g,
    bf16* __restrict__ Chi, float* __restrict__ Cf,
    const float* __restrict__ Text, float* __restrict__ Feat,
    int Ncdim, int Kdim, long sA, long sB, long sC)
{
    __shared__ __align__(16) bf16 lds[2][2][256 * 64];   // 128 KiB

    const int tid = threadIdx.x;
    const int lane = tid & 63;
    const int wv = tid >> 6;
    const int wrow = (wv >> 2) << 7;
    const int wcol = (wv & 3) << 6;
    const int mfrag = lane & 15;
    const int quad = lane >> 4;

    const long z = blockIdx.z;
    const int row0 = blockIdx.y * 256;
    const int col0 = blockIdx.x * 256;

    const bf16* Ab = A_g + z * sA + (long)row0 * Kdim;
    const bf16* Bb = B_g + z * sB + (long)col0 * Kdim;

    f32x4 acc[8][4] = {};
    const int NT = Kdim >> 6;

    stage64(Ab, Kdim, 0, lds[0][0], tid);
    stage64(Bb, Kdim, 0, lds[0][1], tid);

    for (int t = 0; t < NT; ++t) {
        const int cur = t & 1;
        const bf16* LA = lds[cur][0];
        const bf16* LB = lds[cur][1];

        // ---- P1: prefetch t+1, counted wait for t, quadrant (i0-3, j0-1)
        if (t + 1 < NT) {
            const int k0 = (t + 1) << 6;
            stage64(Ab, Kdim, k0, lds[cur ^ 1][0], tid);
            stage64(Bb, Kdim, k0, lds[cur ^ 1][1], tid);
            WAITV8();
        } else {
            WAITV0();
        }
        BARRIER();
        bf16x8 a[4][2], b0[2][2], b1[2][2];
#pragma unroll
        for (int i = 0; i < 4; ++i)
#pragma unroll
            for (int ks = 0; ks < 2; ++ks)
                a[i][ks] = rd64(LA, wrow + i * 16 + mfrag, ks, quad);
#pragma unroll
        for (int j = 0; j < 2; ++j)
#pragma unroll
            for (int ks = 0; ks < 2; ++ks)
                b0[j][ks] = rd64(LB, wcol + j * 16 + mfrag, ks, quad);
        __builtin_amdgcn_s_setprio(1);
#pragma unroll
        for (int i = 0; i < 4; ++i)
#pragma unroll
            for (int j = 0; j < 2; ++j)
#pragma unroll
                for (int ks = 0; ks < 2; ++ks)
                    acc[i][j] = MFMA16(a[i][ks], b0[j][ks], acc[i][j]);
        __builtin_amdgcn_s_setprio(0);
        BARRIER();

        // ---- P2: quadrant (i0-3, j2-3)
#pragma unroll
        for (int j = 0; j < 2; ++j)
#pragma unroll
            for (int ks = 0; ks < 2; ++ks)
                b1[j][ks] = rd64(LB, wcol + (2 + j) * 16 + mfrag, ks, quad);
        BARRIER();
        __builtin_amdgcn_s_setprio(1);
#pragma unroll
        for (int i = 0; i < 4; ++i)
#pragma unroll
            for (int j = 0; j < 2; ++j)
#pragma unroll
                for (int ks = 0; ks < 2; ++ks)
                    acc[i][2 + j] = MFMA16(a[i][ks], b1[j][ks], acc[i][2 + j]);
        __builtin_amdgcn_s_setprio(0);
        BARRIER();

        // ---- P3: quadrant (i4-7, j2-3) — a[] re-read with upper rows
#pragma unroll
        for (int i = 0; i < 4; ++i)
#pragma unroll
            for (int ks = 0; ks < 2; ++ks)
                a[i][ks] = rd64(LA, wrow + (4 + i) * 16 + mfrag, ks, quad);
        BARRIER();
        __builtin_amdgcn_s_setprio(1);
#pragma unroll
        for (int i = 0; i < 4; ++i)
#pragma unroll
            for (int j = 0; j < 2; ++j)
#pragma unroll
                for (int ks = 0; ks < 2; ++ks)
                    acc[4 + i][2 + j] = MFMA16(a[i][ks], b1[j][ks], acc[4 + i][2 + j]);
        __builtin_amdgcn_s_setprio(0);
        BARRIER();

        // ---- P4: quadrant (i4-7, j0-1) — b0 re-read
#pragma unroll
        for (int j = 0; j < 2; ++j)
#pragma unroll
            for (int ks = 0; ks < 2; ++ks)
                b0[j][ks] = rd64(LB, wcol + j * 16 + mfrag, ks, quad);
        BARRIER();
        __builtin_amdgcn_s_setprio(1);
#pragma unroll
        for (int i = 0; i < 4; ++i)
#pragma unroll
            for (int j = 0; j < 2; ++j)
#pragma unroll
                for (int ks = 0; ks < 2; ++ks)
                    acc[4 + i][j] = MFMA16(a[i][ks], b0[j][ks], acc[4 + i][j]);
        __builtin_amdgcn_s_setprio(0);
        BARRIER();
    }

    // ---- epilogue ----
    const long cbase = z * sC;
#pragma unroll
    for (int i = 0; i < 8; ++i) {
#pragma unroll
        for (int r = 0; r < 4; ++r) {
            int row = row0 + wrow + i * 16 + quad * 4 + r;
            long rbase = cbase + (long)row * Ncdim;
#pragma unroll
            for (int j = 0; j < 4; ++j) {
                int col = col0 + wcol + j * 16 + mfrag;
                float v = acc[i][j][r];
                if constexpr (EPI == 0) {
                    Chi[rbase + col] = (bf16)v;
                } else {
                    Cf[rbase + col] = v;
                    Feat[rbase + col] = v + Text[rbase + col];
                }
            }
        }
    }
}

// ---------------------------------------------------------------------------
// Column softmax over the QUERY axis, throughput version (round-4 verified).
// ---------------------------------------------------------------------------
__global__ __launch_bounds__(1024) void col_softmax_bf16(const float* __restrict__ S,
                                                         bf16* __restrict__ Aout)
{
    const int b = blockIdx.x / (N / 64);
    const int mbase = (blockIdx.x % (N / 64)) * 64;
    const int t = threadIdx.x;
    const int mloc = t & 63;
    const int slice = t >> 6;             // 0..15
    const int m = mbase + mloc;
    const float* Sb = S + (size_t)b * N * N;
    bf16* Ab = Aout + (size_t)b * N * N;
    const int n_lo = slice * (N / 16), n_hi = n_lo + (N / 16);   // 128 rows

    __shared__ float red_m[16][64];
    __shared__ float red_s[16][64];

    float mx = -INFINITY, s = 0.0f;
    for (int n = n_lo; n < n_hi; n += 8) {
        float x[8];
#pragma unroll
        for (int u = 0; u < 8; ++u) x[u] = Sb[(size_t)(n + u) * N + m];
        float bm = x[0];
#pragma unroll
        for (int u = 1; u < 8; ++u) bm = fmaxf(bm, x[u]);
        float nm = fmaxf(mx, bm);
        float a = 0.0f;
#pragma unroll
        for (int u = 0; u < 8; ++u) a += __expf(x[u] - nm);
        s = s * __expf(mx - nm) + a;
        mx = nm;
    }
    red_m[slice][mloc] = mx;
    red_s[slice][mloc] = s;
    __syncthreads();

    float gm = -INFINITY;
#pragma unroll
    for (int i = 0; i < 16; ++i) gm = fmaxf(gm, red_m[i][mloc]);
    float den = 0.0f;
#pragma unroll
    for (int i = 0; i < 16; ++i) den += red_s[i][mloc] * __expf(red_m[i][mloc] - gm);
    float inv = 1.0f / den;

    for (int n = n_lo; n < n_hi; n += 8) {
        float x[8];
#pragma unroll
        for (int u = 0; u < 8; ++u) x[u] = Sb[(size_t)(n + u) * N + m];
#pragma unroll
        for (int u = 0; u < 8; ++u)
            Ab[(size_t)(n + u) * N + m] = (bf16)(__expf(x[u] - gm) * inv);
    }
}

// ---------------------------------------------------------------------------
extern "C" void kernel_launch(void* const* d_in, const int* in_sizes, int n_in,
                              void* d_out, int out_size, void* d_ws, size_t ws_size,
                              hipStream_t stream)
{
    const float* img  = (const float*)d_in[0];
    const float* text = (const float*)d_in[1];
    const float* Wq   = (const float*)d_in[2];
    const float* Wk   = (const float*)d_in[3];
    const float* Wv   = (const float*)d_in[4];

    const long E  = (long)B * N * D;   // 16.78M
    const long W2 = (long)D * D;       // 1.05M
    const long EN = (long)B * N * N;   // 33.55M

    // ws layout identical to the verified round-1 plan (201.3 MB).
    char* ws = (char*)d_ws;
    float* S     = (float*)ws;
    bf16* img_h  = (bf16*)ws;
    bf16* img_l  = img_h + E;
    bf16* WqT_h  = (bf16*)(ws + (size_t)4 * E);
    bf16* WqT_l  = WqT_h + W2;
    bf16* WkT_h  = WqT_l + W2;
    bf16* WkT_l  = WkT_h + W2;
    bf16* Wqk_h  = WkT_l + W2;
    bf16* Wqk_l  = Wqk_h + W2;
    bf16* Wv_l_s = Wqk_l + W2;
    float* out_pv = (float*)ws;            // S region, dead after softmax

    bf16* text_h = (bf16*)(ws + (size_t)EN * 4);
    bf16* text_l = text_h + E;
    bf16* VT_h   = text_l;                 // recycled after S GEMM

    bf16* T_h  = (bf16*)d_out;
    bf16* T_l  = T_h + E;
    bf16* Wv_h = T_l + E;
    bf16* alpha = (bf16*)d_out;
    float* out  = (float*)d_out;
    float* feat = out + E;

    dim3 blk(256);
    dim3 blk5(512);

    // 1. splits
    split_fp32<<<E / 1024, blk, 0, stream>>>(img,  img_h,  img_l,  E);
    split_fp32<<<E / 1024, blk, 0, stream>>>(text, text_h, text_l, E);
    split_fp32<<<W2 / 1024, blk, 0, stream>>>(Wv, Wv_h, Wv_l_s, W2);
    tsplit_1024<<<dim3(16, 16), blk, 0, stream>>>(Wq, WqT_h, WqT_l);
    tsplit_1024<<<dim3(16, 16), blk, 0, stream>>>(Wk, WkT_h, WkT_l);

    // 2. Wqk'[i,j] = sum_k Wk[k,i] * Wq[k,j]  (tiny: stay on 128^2 kernel)
    gemm_nt_mfma<3, 0><<<dim3(8, 8, 1), blk, 0, stream>>>(
        WkT_h, WkT_l, WqT_h, WqT_l, Wqk_h, Wqk_l, nullptr, nullptr, nullptr,
        D, D, D, 0, 0, 0);

    // 3. T = img @ Wqk  (split out to T_h/T_l in d_out) — 256^2 phased
    gemm256_3t<0><<<dim3(D / 256, (B * N) / 256, 1), blk5, 0, stream>>>(
        img_h, img_l, Wqk_h, Wqk_l, T_h, T_l, nullptr,
        D, D, 0, 0, 0);

    // 4. S[b] = T[b] @ text[b]^T  (3-term, fp32) — 256^2 phased
    gemm256_3t<1><<<dim3(N / 256, N / 256, B), blk5, 0, stream>>>(
        T_h, T_l, text_h, text_l, nullptr, nullptr, S,
        N, D, (long)N * D, (long)N * D, (long)N * N);

    // 5. VT[b][v][m] = sum_d Wv[v,d] * text[b,m,d] — 256^2 phased, 1-term
    gemm256_1t<0><<<dim3(N / 256, D / 256, B), blk5, 0, stream>>>(
        Wv_h, text_h, VT_h, nullptr, nullptr, nullptr,
        N, D, 0, (long)N * D, (long)D * N);

    // 6. softmax over query axis; S fp32 -> alpha bf16
    col_softmax_bf16<<<dim3(B * N / 64), dim3(1024), 0, stream>>>(S, alpha);

    // 7. out = alpha @ VT^T ; feat = out + text — 256^2 phased, 1-term
    gemm256_1t<2><<<dim3(D / 256, N / 256, B), blk5, 0, stream>>>(
        alpha, VT_h, nullptr, out_pv, text, feat,
        N * 0 + D, N, (long)N * N, (long)D * N, (long)N * D);

    // 8. move `out` home (alpha occupied d_out[0..4E) during PV)
    hipMemcpyAsync(out, out_pv, (size_t)E * 4, hipMemcpyDeviceToDevice, stream);
}

// Round 2
// 738.033 us; speedup vs baseline: 1.2473x; 1.0451x over previous
//
#include <hip/hip_runtime.h>
#include <math.h>

#define B 8
#define N 2048
#define D 1024

#define BM 128
#define BN 128
#define BK 32

typedef __bf16 bf16;
typedef __bf16 bf16x8 __attribute__((ext_vector_type(8)));
typedef __bf16 bf16x4 __attribute__((ext_vector_type(4)));
typedef float f32x4 __attribute__((ext_vector_type(4)));

__device__ __forceinline__ void load_lds16(const void* g, void* l) {
    __builtin_amdgcn_global_load_lds((const __attribute__((address_space(1))) void*)g,
                                     (__attribute__((address_space(3))) void*)l, 16, 0, 0);
}

#define MFMA16(a, b, c) __builtin_amdgcn_mfma_f32_16x16x32_bf16(a, b, c, 0, 0, 0)
#define BARRIER() asm volatile("s_barrier" ::: "memory")
#define WAITV0() asm volatile("s_waitcnt vmcnt(0)" ::: "memory")

// ---------------------------------------------------------------------------
// Split fp32 x into bf16 hi + lo residual (hi = RN(x), lo = RN(x - hi)).
// ---------------------------------------------------------------------------
__global__ __launch_bounds__(256) void split_fp32(const float* __restrict__ x,
                                                  bf16* __restrict__ h,
                                                  bf16* __restrict__ l, long n)
{
    long i = ((long)blockIdx.x * 256 + threadIdx.x) * 4;
    if (i >= n) return;
    float4 v = *(const float4*)(x + i);
    float vs[4] = {v.x, v.y, v.z, v.w};
    bf16x4 hh, ll;
#pragma unroll
    for (int t = 0; t < 4; ++t) {
        bf16 hv = (bf16)vs[t];
        hh[t] = hv;
        ll[t] = (bf16)(vs[t] - (float)hv);
    }
    *(bf16x4*)(h + i) = hh;
    *(bf16x4*)(l + i) = ll;
}

// ---------------------------------------------------------------------------
// Transpose + split: W [1024][1024] fp32 -> WT_h/WT_l bf16, WT[d][k]=W[k][d].
// ---------------------------------------------------------------------------
__global__ __launch_bounds__(256) void tsplit_1024(const float* __restrict__ W,
                                                   bf16* __restrict__ WT_h,
                                                   bf16* __restrict__ WT_l)
{
    __shared__ float tile[64][65];
    const int d0 = blockIdx.x * 64, k0 = blockIdx.y * 64;
    const int tx = threadIdx.x & 63, ty = threadIdx.x >> 6;
#pragma unroll
    for (int r = 0; r < 16; ++r) {
        int kl = ty + r * 4;
        tile[kl][tx] = W[(size_t)(k0 + kl) * 1024 + d0 + tx];
    }
    __syncthreads();
#pragma unroll
    for (int r = 0; r < 16; ++r) {
        int dl = ty + r * 4;
        float v = tile[tx][dl];
        bf16 hv = (bf16)v;
        size_t idx = (size_t)(d0 + dl) * 1024 + k0 + tx;
        WT_h[idx] = hv;
        WT_l[idx] = (bf16)(v - (float)hv);
    }
}

// ---------------------------------------------------------------------------
// Old 128x128 NT MFMA GEMM (m97 structure) — kept ONLY for the tiny 1024^3
// Wqk product (needs 64 small blocks for occupancy, perf-irrelevant).
// ---------------------------------------------------------------------------
template<int TERMS, int EPI>
__global__ __launch_bounds__(256) void gemm_nt_mfma(
    const bf16* __restrict__ Ah_g, const bf16* __restrict__ Al_g,
    const bf16* __restrict__ Bh_g, const bf16* __restrict__ Bl_g,
    bf16* __restrict__ Chi, bf16* __restrict__ Clo,
    float* __restrict__ Cf, const float* __restrict__ Text,
    float* __restrict__ Feat,
    int Mdim, int Ncdim, int Kdim, long sA, long sB, long sC)
{
    __shared__ bf16 Ah[BM][BK];
    __shared__ bf16 Bh[BN][BK];
    __shared__ bf16 Al[BM][BK];
    __shared__ bf16 Bl[BN][BK];

    const int tid = threadIdx.x;
    const int lane = tid & 63;
    const int wv = tid >> 6;
    const int wr = (wv >> 1) * 64;
    const int wc = (wv & 1) * 64;
    const int mfrag = lane & 15;
    const int quad = lane >> 4;

    const long z = blockIdx.z;
    const int row0 = blockIdx.y * BM;
    const int col0 = blockIdx.x * BN;

    const bf16* Abh = Ah_g + z * sA;
    const bf16* Abl = (TERMS == 3) ? (Al_g + z * sA) : nullptr;
    const bf16* Bbh = Bh_g + z * sB;
    const bf16* Bbl = (TERMS == 3) ? (Bl_g + z * sB) : nullptr;

    f32x4 acc[4][4] = {};

    for (int k0 = 0; k0 < Kdim; k0 += BK) {
#pragma unroll
        for (int q = 0; q < 2; ++q) {
            int c = q * 256 + tid;
            int row = c >> 2, kp = (c & 3) * 8;
            load_lds16(Abh + (long)(row0 + row) * Kdim + k0 + kp, &Ah[row][kp]);
            load_lds16(Bbh + (long)(col0 + row) * Kdim + k0 + kp, &Bh[row][kp]);
            if constexpr (TERMS == 3) {
                load_lds16(Abl + (long)(row0 + row) * Kdim + k0 + kp, &Al[row][kp]);
                load_lds16(Bbl + (long)(col0 + row) * Kdim + k0 + kp, &Bl[row][kp]);
            }
        }
        __syncthreads();

        bf16x8 a_h[4], b_h[4], a_l[4], b_l[4];
#pragma unroll
        for (int i = 0; i < 4; ++i) {
            a_h[i] = *(const bf16x8*)&Ah[wr + i * 16 + mfrag][quad * 8];
            b_h[i] = *(const bf16x8*)&Bh[wc + i * 16 + mfrag][quad * 8];
            if constexpr (TERMS == 3) {
                a_l[i] = *(const bf16x8*)&Al[wr + i * 16 + mfrag][quad * 8];
                b_l[i] = *(const bf16x8*)&Bl[wc + i * 16 + mfrag][quad * 8];
            }
        }
#pragma unroll
        for (int i = 0; i < 4; ++i)
#pragma unroll
            for (int j = 0; j < 4; ++j) {
                acc[i][j] = MFMA16(a_h[i], b_h[j], acc[i][j]);
                if constexpr (TERMS == 3) {
                    acc[i][j] = MFMA16(a_h[i], b_l[j], acc[i][j]);
                    acc[i][j] = MFMA16(a_l[i], b_h[j], acc[i][j]);
                }
            }
        __syncthreads();
    }

    const long cbase = z * sC;
    const bool wlo = (Clo != nullptr);
#pragma unroll
    for (int i = 0; i < 4; ++i) {
#pragma unroll
        for (int r = 0; r < 4; ++r) {
            int row = row0 + wr + i * 16 + quad * 4 + r;
#pragma unroll
            for (int j = 0; j < 4; ++j) {
                int col = col0 + wc + j * 16 + mfrag;
                long idx = cbase + (long)row * Ncdim + col;
                float v = acc[i][j][r];
                if constexpr (EPI == 0) {
                    bf16 h = (bf16)v;
                    Chi[idx] = h;
                    if (wlo) Clo[idx] = (bf16)(v - (float)h);
                } else if constexpr (EPI == 1) {
                    Cf[idx] = v;
                } else {
                    Cf[idx] = v;
                    Feat[idx] = v + Text[idx];
                }
            }
        }
    }
}

// ===========================================================================
// 256x256-tile 8-wave GEMMs, round 2: software-pipelined counted-wait
// schedule. ONE barrier per K-tile; within the tile each ds_read group is
// issued one MFMA-cluster ahead of its consumer so the compiler's counted
// lgkmcnt overlaps LDS processing with the matrix pipe (round-1's
// barrier-lockstep serialized them: LDS 2300cy + MFMA 3100cy per tile).
// Stages for t+1 are issued mid-tile; the single vmcnt(0) at the tile top
// only drains loads >= ~2 MFMA-clusters old (>1000 cyc), so it's free.
// T2 XOR swizzle (bank-conflict 0, verified round 1) and T5 setprio kept.
// T1 XCD-aware block swizzle added (all grids have nwg % 8 == 0).
// Numerics: per-accumulator MFMA order identical -> bit-identical output.
// ===========================================================================

__device__ __forceinline__ void xcd_swz(int& bx, int& by, int gx, int gy) {
    int nwg = gx * gy;
    int flat = by * gx + bx;
    flat = (flat & 7) * (nwg >> 3) + (flat >> 3);   // bijective: nwg % 8 == 0
    bx = flat % gx;
    by = flat / gx;
}

// stage a 256-row x 32-col bf16 panel; LDS linear, source pre-swizzled.
__device__ __forceinline__ void stage32(const bf16* __restrict__ g, int Kd, int k0,
                                        bf16* l, int tid)
{
#pragma unroll
    for (int c = 0; c < 2; ++c) {
        int idx = c * 512 + tid;
        int row = idx >> 2;
        int slot = idx & 3;
        int kk = ((slot ^ ((row >> 1) & 3)) << 3);
        load_lds16(g + (long)row * Kd + k0 + kk, l + (size_t)idx * 8);
    }
}

// stage a 256-row x 64-col bf16 panel; LDS linear, source pre-swizzled.
__device__ __forceinline__ void stage64(const bf16* __restrict__ g, int Kd, int k0,
                                        bf16* l, int tid)
{
#pragma unroll
    for (int c = 0; c < 4; ++c) {
        int idx = c * 512 + tid;
        int row = idx >> 3;
        int slot = idx & 7;
        int kk = ((slot ^ (row & 7)) << 3);
        load_lds16(g + (long)row * Kd + k0 + kk, l + (size_t)idx * 8);
    }
}

__device__ __forceinline__ bf16x8 rd32(const bf16* l, int row, int quad) {
    return *(const bf16x8*)(l + row * 32 + ((quad ^ ((row >> 1) & 3)) << 3));
}
__device__ __forceinline__ bf16x8 rd64(const bf16* l, int row, int ks, int quad) {
    return *(const bf16x8*)(l + row * 64 + (((ks * 4 + quad) ^ (row & 7)) << 3));
}

// ---------------------------------------------------------------------------
// 3-term split-bf16 GEMM, BK=32, pipelined 6-cluster schedule.
// EPI: 0 = write bf16 hi (+lo if Clo), 1 = write fp32 Cf.
// ---------------------------------------------------------------------------
template<int EPI>
__global__ __launch_bounds__(512) void gemm256_3t(
    const bf16* __restrict__ Ah_g, const bf16* __restrict__ Al_g,
    const bf16* __restrict__ Bh_g, const bf16* __restrict__ Bl_g,
    bf16* __restrict__ Chi, bf16* __restrict__ Clo, float* __restrict__ Cf,
    int Ncdim, int Kdim, long sA, long sB, long sC)
{
    __shared__ __align__(16) bf16 lds[2][4][256 * 32];   // 128 KiB

    const int tid = threadIdx.x;
    const int lane = tid & 63;
    const int wv = tid >> 6;
    const int wrow = (wv >> 2) << 7;
    const int wcol = (wv & 3) << 6;
    const int mfrag = lane & 15;
    const int quad = lane >> 4;

    const long z = blockIdx.z;
    int bx = blockIdx.x, by = blockIdx.y;
    xcd_swz(bx, by, gridDim.x, gridDim.y);
    const int row0 = by * 256;
    const int col0 = bx * 256;

    const bf16* Abh = Ah_g + z * sA + (long)row0 * Kdim;
    const bf16* Abl = Al_g + z * sA + (long)row0 * Kdim;
    const bf16* Bbh = Bh_g + z * sB + (long)col0 * Kdim;
    const bf16* Bbl = Bl_g + z * sB + (long)col0 * Kdim;

    f32x4 acc[8][4] = {};
    const int NT = Kdim >> 5;

    // prologue: stage tile 0
    stage32(Abh, Kdim, 0, lds[0][0], tid);
    stage32(Bbh, Kdim, 0, lds[0][2], tid);
    stage32(Abl, Kdim, 0, lds[0][1], tid);
    stage32(Bbl, Kdim, 0, lds[0][3], tid);

    for (int t = 0; t < NT; ++t) {
        const int cur = t & 1;
        const bf16* LAh = lds[cur][0];
        const bf16* LAl = lds[cur][1];
        const bf16* LBh = lds[cur][2];
        const bf16* LBl = lds[cur][3];
        const bool pf = (t + 1 < NT);
        const int kn = (t + 1) << 5;

        // tile-boundary guard: own stages drained, then publish via barrier.
        WAITV0();
        BARRIER();

        // R1+R2: A-hi rows + B-hi cols
        bf16x8 ah[8], bh[4], bl[4], al[8];
#pragma unroll
        for (int i = 0; i < 8; ++i) ah[i] = rd32(LAh, wrow + i * 16 + mfrag, quad);
#pragma unroll
        for (int j = 0; j < 4; ++j) bh[j] = rd32(LBh, wcol + j * 16 + mfrag, quad);

        // M1: hh, lower half
        __builtin_amdgcn_s_setprio(1);
#pragma unroll
        for (int i = 0; i < 4; ++i)
#pragma unroll
            for (int j = 0; j < 4; ++j)
                acc[i][j] = MFMA16(ah[i], bh[j], acc[i][j]);
        __builtin_amdgcn_s_setprio(0);

        if (pf) { stage32(Abh, Kdim, kn, lds[cur ^ 1][0], tid);
                  stage32(Bbh, Kdim, kn, lds[cur ^ 1][2], tid); }

        // R3: B-lo
#pragma unroll
        for (int j = 0; j < 4; ++j) bl[j] = rd32(LBl, wcol + j * 16 + mfrag, quad);

        // M2: hh, upper half
        __builtin_amdgcn_s_setprio(1);
#pragma unroll
        for (int i = 4; i < 8; ++i)
#pragma unroll
            for (int j = 0; j < 4; ++j)
                acc[i][j] = MFMA16(ah[i], bh[j], acc[i][j]);
        __builtin_amdgcn_s_setprio(0);

        // R4: A-lo lower
#pragma unroll
        for (int i = 0; i < 4; ++i) al[i] = rd32(LAl, wrow + i * 16 + mfrag, quad);

        // M3: hl, lower half
        __builtin_amdgcn_s_setprio(1);
#pragma unroll
        for (int i = 0; i < 4; ++i)
#pragma unroll
            for (int j = 0; j < 4; ++j)
                acc[i][j] = MFMA16(ah[i], bl[j], acc[i][j]);
        __builtin_amdgcn_s_setprio(0);

        if (pf) { stage32(Abl, Kdim, kn, lds[cur ^ 1][1], tid);
                  stage32(Bbl, Kdim, kn, lds[cur ^ 1][3], tid); }

        // R5: A-lo upper
#pragma unroll
        for (int i = 4; i < 8; ++i) al[i] = rd32(LAl, wrow + i * 16 + mfrag, quad);

        // M4: hl, upper half
        __builtin_amdgcn_s_setprio(1);
#pragma unroll
        for (int i = 4; i < 8; ++i)
#pragma unroll
            for (int j = 0; j < 4; ++j)
                acc[i][j] = MFMA16(ah[i], bl[j], acc[i][j]);

        // M5+M6: lh, both halves
#pragma unroll
        for (int i = 0; i < 8; ++i)
#pragma unroll
            for (int j = 0; j < 4; ++j)
                acc[i][j] = MFMA16(al[i], bh[j], acc[i][j]);
        __builtin_amdgcn_s_setprio(0);
    }

    // ---- epilogue ---- C/D layout: col = lane&15, row = quad*4 + reg
    const long cbase = z * sC;
    const bool wlo = (Clo != nullptr);
#pragma unroll
    for (int i = 0; i < 8; ++i) {
#pragma unroll
        for (int r = 0; r < 4; ++r) {
            int row = row0 + wrow + i * 16 + quad * 4 + r;
            long rbase = cbase + (long)row * Ncdim;
#pragma unroll
            for (int j = 0; j < 4; ++j) {
                int col = col0 + wcol + j * 16 + mfrag;
                float v = acc[i][j][r];
                if constexpr (EPI == 0) {
                    bf16 h = (bf16)v;
                    Chi[rbase + col] = h;
                    if (wlo) Clo[rbase + col] = (bf16)(v - (float)h);
                } else {
                    Cf[rbase + col] = v;
                }
            }
        }
    }
}

// ---------------------------------------------------------------------------
// 1-term GEMM, BK=64, pipelined 4-cluster schedule.
// EPI: 0 = write bf16 hi ; 2 = PV epilogue (Cf = C fp32, Feat = C + Text).
// ---------------------------------------------------------------------------
template<int EPI>
__global__ __launch_bounds__(512) void gemm256_1t(
    const bf16* __restrict__ A_g, const bf16* __restrict__ B_g,
    bf16* __restrict__ Chi, float* __restrict__ Cf,
    const float* __restrict__ Text, float* __restrict__ Feat,
    int Ncdim, int Kdim, long sA, long sB, long sC)
{
    __shared__ __align__(16) bf16 lds[2][2][256 * 64];   // 128 KiB

    const int tid = threadIdx.x;
    const int lane = tid & 63;
    const int wv = tid >> 6;
    const int wrow = (wv >> 2) << 7;
    const int wcol = (wv & 3) << 6;
    const int mfrag = lane & 15;
    const int quad = lane >> 4;

    const long z = blockIdx.z;
    int bx = blockIdx.x, by = blockIdx.y;
    xcd_swz(bx, by, gridDim.x, gridDim.y);
    const int row0 = by * 256;
    const int col0 = bx * 256;

    const bf16* Ab = A_g + z * sA + (long)row0 * Kdim;
    const bf16* Bb = B_g + z * sB + (long)col0 * Kdim;

    f32x4 acc[8][4] = {};
    const int NT = Kdim >> 6;

    stage64(Ab, Kdim, 0, lds[0][0], tid);
    stage64(Bb, Kdim, 0, lds[0][1], tid);

    for (int t = 0; t < NT; ++t) {
        const int cur = t & 1;
        const bf16* LA = lds[cur][0];
        const bf16* LB = lds[cur][1];
        const bool pf = (t + 1 < NT);
        const int kn = (t + 1) << 6;

        WAITV0();
        BARRIER();

        bf16x8 a[8][2], b[4][2];
        // R1: A rows 0-3, B cols 0-1
#pragma unroll
        for (int i = 0; i < 4; ++i)
#pragma unroll
            for (int ks = 0; ks < 2; ++ks)
                a[i][ks] = rd64(LA, wrow + i * 16 + mfrag, ks, quad);
#pragma unroll
        for (int j = 0; j < 2; ++j)
#pragma unroll
            for (int ks = 0; ks < 2; ++ks)
                b[j][ks] = rd64(LB, wcol + j * 16 + mfrag, ks, quad);

        // M1: (i0-3, j0-1)
        __builtin_amdgcn_s_setprio(1);
#pragma unroll
        for (int i = 0; i < 4; ++i)
#pragma unroll
            for (int j = 0; j < 2; ++j)
#pragma unroll
                for (int ks = 0; ks < 2; ++ks)
                    acc[i][j] = MFMA16(a[i][ks], b[j][ks], acc[i][j]);
        __builtin_amdgcn_s_setprio(0);

        if (pf) stage64(Ab, Kdim, kn, lds[cur ^ 1][0], tid);

        // R2: B cols 2-3
#pragma unroll
        for (int j = 2; j < 4; ++j)
#pragma unroll
            for (int ks = 0; ks < 2; ++ks)
                b[j][ks] = rd64(LB, wcol + j * 16 + mfrag, ks, quad);

        // M2: (i0-3, j2-3)
        __builtin_amdgcn_s_setprio(1);
#pragma unroll
        for (int i = 0; i < 4; ++i)
#pragma unroll
            for (int j = 2; j < 4; ++j)
#pragma unroll
                for (int ks = 0; ks < 2; ++ks)
                    acc[i][j] = MFMA16(a[i][ks], b[j][ks], acc[i][j]);
        __builtin_amdgcn_s_setprio(0);

        // R3: A rows 4-7
#pragma unroll
        for (int i = 4; i < 8; ++i)
#pragma unroll
            for (int ks = 0; ks < 2; ++ks)
                a[i][ks] = rd64(LA, wrow + i * 16 + mfrag, ks, quad);

        // M3: (i4-7, j2-3)
        __builtin_amdgcn_s_setprio(1);
#pragma unroll
        for (int i = 4; i < 8; ++i)
#pragma unroll
            for (int j = 2; j < 4; ++j)
#pragma unroll
                for (int ks = 0; ks < 2; ++ks)
                    acc[i][j] = MFMA16(a[i][ks], b[j][ks], acc[i][j]);
        __builtin_amdgcn_s_setprio(0);

        if (pf) stage64(Bb, Kdim, kn, lds[cur ^ 1][1], tid);

        // M4: (i4-7, j0-1)
        __builtin_amdgcn_s_setprio(1);
#pragma unroll
        for (int i = 4; i < 8; ++i)
#pragma unroll
            for (int j = 0; j < 2; ++j)
#pragma unroll
                for (int ks = 0; ks < 2; ++ks)
                    acc[i][j] = MFMA16(a[i][ks], b[j][ks], acc[i][j]);
        __builtin_amdgcn_s_setprio(0);
    }

    // ---- epilogue ----
    const long cbase = z * sC;
#pragma unroll
    for (int i = 0; i < 8; ++i) {
#pragma unroll
        for (int r = 0; r < 4; ++r) {
            int row = row0 + wrow + i * 16 + quad * 4 + r;
            long rbase = cbase + (long)row * Ncdim;
#pragma unroll
            for (int j = 0; j < 4; ++j) {
                int col = col0 + wcol + j * 16 + mfrag;
                float v = acc[i][j][r];
                if constexpr (EPI == 0) {
                    Chi[rbase + col] = (bf16)v;
                } else {
                    Cf[rbase + col] = v;
                    Feat[rbase + col] = v + Text[rbase + col];
                }
            }
        }
    }
}

// ---------------------------------------------------------------------------
// Column softmax over the QUERY axis (round-4 verified).
// ---------------------------------------------------------------------------
__global__ __launch_bounds__(1024) void col_softmax_bf16(const float* __restrict__ S,
                                                         bf16* __restrict__ Aout)
{
    const int b = blockIdx.x / (N / 64);
    const int mbase = (blockIdx.x % (N / 64)) * 64;
    const int t = threadIdx.x;
    const int mloc = t & 63;
    const int slice = t >> 6;
    const int m = mbase + mloc;
    const float* Sb = S + (size_t)b * N * N;
    bf16* Ab = Aout + (size_t)b * N * N;
    const int n_lo = slice * (N / 16), n_hi = n_lo + (N / 16);

    __shared__ float red_m[16][64];
    __shared__ float red_s[16][64];

    float mx = -INFINITY, s = 0.0f;
    for (int n = n_lo; n < n_hi; n += 8) {
        float x[8];
#pragma unroll
        for (int u = 0; u < 8; ++u) x[u] = Sb[(size_t)(n + u) * N + m];
        float bm = x[0];
#pragma unroll
        for (int u = 1; u < 8; ++u) bm = fmaxf(bm, x[u]);
        float nm = fmaxf(mx, bm);
        float a = 0.0f;
#pragma unroll
        for (int u = 0; u < 8; ++u) a += __expf(x[u] - nm);
        s = s * __expf(mx - nm) + a;
        mx = nm;
    }
    red_m[slice][mloc] = mx;
    red_s[slice][mloc] = s;
    __syncthreads();

    float gm = -INFINITY;
#pragma unroll
    for (int i = 0; i < 16; ++i) gm = fmaxf(gm, red_m[i][mloc]);
    float den = 0.0f;
#pragma unroll
    for (int i = 0; i < 16; ++i) den += red_s[i][mloc] * __expf(red_m[i][mloc] - gm);
    float inv = 1.0f / den;

    for (int n = n_lo; n < n_hi; n += 8) {
        float x[8];
#pragma unroll
        for (int u = 0; u < 8; ++u) x[u] = Sb[(size_t)(n + u) * N + m];
#pragma unroll
        for (int u = 0; u < 8; ++u)
            Ab[(size_t)(n + u) * N + m] = (bf16)(__expf(x[u] - gm) * inv);
    }
}

// ---------------------------------------------------------------------------
extern "C" void kernel_launch(void* const* d_in, const int* in_sizes, int n_in,
                              void* d_out, int out_size, void* d_ws, size_t ws_size,
                              hipStream_t stream)
{
    const float* img  = (const float*)d_in[0];
    const float* text = (const float*)d_in[1];
    const float* Wq   = (const float*)d_in[2];
    const float* Wk   = (const float*)d_in[3];
    const float* Wv   = (const float*)d_in[4];

    const long E  = (long)B * N * D;   // 16.78M
    const long W2 = (long)D * D;       // 1.05M
    const long EN = (long)B * N * N;   // 33.55M

    // ws layout identical to the verified round-1 plan (201.3 MB).
    char* ws = (char*)d_ws;
    float* S     = (float*)ws;
    bf16* img_h  = (bf16*)ws;
    bf16* img_l  = img_h + E;
    bf16* WqT_h  = (bf16*)(ws + (size_t)4 * E);
    bf16* WqT_l  = WqT_h + W2;
    bf16* WkT_h  = WqT_l + W2;
    bf16* WkT_l  = WkT_h + W2;
    bf16* Wqk_h  = WkT_l + W2;
    bf16* Wqk_l  = Wqk_h + W2;
    bf16* Wv_l_s = Wqk_l + W2;
    float* out_pv = (float*)ws;            // S region, dead after softmax

    bf16* text_h = (bf16*)(ws + (size_t)EN * 4);
    bf16* text_l = text_h + E;
    bf16* VT_h   = text_l;                 // recycled after S GEMM

    bf16* T_h  = (bf16*)d_out;
    bf16* T_l  = T_h + E;
    bf16* Wv_h = T_l + E;
    bf16* alpha = (bf16*)d_out;
    float* out  = (float*)d_out;
    float* feat = out + E;

    dim3 blk(256);
    dim3 blk5(512);

    // 1. splits
    split_fp32<<<E / 1024, blk, 0, stream>>>(img,  img_h,  img_l,  E);
    split_fp32<<<E / 1024, blk, 0, stream>>>(text, text_h, text_l, E);
    split_fp32<<<W2 / 1024, blk, 0, stream>>>(Wv, Wv_h, Wv_l_s, W2);
    tsplit_1024<<<dim3(16, 16), blk, 0, stream>>>(Wq, WqT_h, WqT_l);
    tsplit_1024<<<dim3(16, 16), blk, 0, stream>>>(Wk, WkT_h, WkT_l);

    // 2. Wqk'[i,j] = sum_k Wk[k,i] * Wq[k,j]  (tiny: stay on 128^2 kernel)
    gemm_nt_mfma<3, 0><<<dim3(8, 8, 1), blk, 0, stream>>>(
        WkT_h, WkT_l, WqT_h, WqT_l, Wqk_h, Wqk_l, nullptr, nullptr, nullptr,
        D, D, D, 0, 0, 0);

    // 3. T = img @ Wqk  (split out to T_h/T_l in d_out) — 256^2 pipelined
    gemm256_3t<0><<<dim3(D / 256, (B * N) / 256, 1), blk5, 0, stream>>>(
        img_h, img_l, Wqk_h, Wqk_l, T_h, T_l, nullptr,
        D, D, 0, 0, 0);

    // 4. S[b] = T[b] @ text[b]^T  (3-term, fp32) — 256^2 pipelined
    gemm256_3t<1><<<dim3(N / 256, N / 256, B), blk5, 0, stream>>>(
        T_h, T_l, text_h, text_l, nullptr, nullptr, S,
        N, D, (long)N * D, (long)N * D, (long)N * N);

    // 5. VT[b][v][m] = sum_d Wv[v,d] * text[b,m,d] — 256^2 pipelined, 1-term
    gemm256_1t<0><<<dim3(N / 256, D / 256, B), blk5, 0, stream>>>(
        Wv_h, text_h, VT_h, nullptr, nullptr, nullptr,
        N, D, 0, (long)N * D, (long)D * N);

    // 6. softmax over query axis; S fp32 -> alpha bf16
    col_softmax_bf16<<<dim3(B * N / 64), dim3(1024), 0, stream>>>(S, alpha);

    // 7. out = alpha @ VT^T ; feat = out + text — 256^2 pipelined, 1-term
    gemm256_1t<2><<<dim3(D / 256, N / 256, B), blk5, 0, stream>>>(
        alpha, VT_h, nullptr, out_pv, text, feat,
        D, N, (long)N * N, (long)D * N, (long)N * D);

    // 8. move `out` home (alpha occupied d_out[0..4E) during PV)
    hipMemcpyAsync(out, out_pv, (size_t)E * 4, hipMemcpyDeviceToDevice, stream);
}